// Round 2
// baseline (3592.630 us; speedup 1.0000x reference)
//
#include <hip/hip_runtime.h>
#include <hip/hip_bf16.h>
#include <stdint.h>
#include <stddef.h>

// Problem constants (fixed by the reference)
#define NN 100000          // nodes
#define NE 3200000         // edges
#define NCHUNK 64          // chunks for stable counting sort
#define CHSZ (NE / NCHUNK) // 50000 edges per chunk
#define NCAND 1024
#define SCAN_BLOCKS 98     // ceil((NN+1)/1024)

// ---------------- threefry2x32, exact JAX lowering ----------------
__host__ __device__ inline void tf2x32(uint32_t k0, uint32_t k1,
                                       uint32_t x0, uint32_t x1,
                                       uint32_t& y0, uint32_t& y1) {
  uint32_t ks2 = k0 ^ k1 ^ 0x1BD11BDAu;
  x0 += k0; x1 += k1;
#define TFR(r) { x0 += x1; x1 = (x1 << (r)) | (x1 >> (32 - (r))); x1 ^= x0; }
  TFR(13) TFR(15) TFR(26) TFR(6)
  x0 += k1;  x1 += ks2 + 1u;
  TFR(17) TFR(29) TFR(16) TFR(24)
  x0 += ks2; x1 += k0 + 2u;
  TFR(13) TFR(15) TFR(26) TFR(6)
  x0 += k0;  x1 += k1 + 3u;
  TFR(17) TFR(29) TFR(16) TFR(24)
  x0 += k1;  x1 += ks2 + 4u;
  TFR(13) TFR(15) TFR(26) TFR(6)
  x0 += ks2; x1 += k0 + 5u;
#undef TFR
  y0 = x0; y1 = x1;
}

// partitionable random_bits(key,32,(n,)): element i -> y0^y1 of tf(key,(0,i));
// uniform: bitcast((bits>>9)|0x3F800000) - 1
__device__ inline float u01_from_key(uint32_t ka, uint32_t kb, uint32_t idx) {
  uint32_t y0, y1; tf2x32(ka, kb, 0u, idx, y0, y1);
  uint32_t bits = y0 ^ y1;
  return __uint_as_float((bits >> 9) | 0x3F800000u) - 1.0f;
}

// numpy pairwise sum for 64 contiguous f32 (8 accumulators + tree combine)
__device__ inline float np_sum64(const float* a) {
#pragma clang fp contract(off)
  float r0=a[0],r1=a[1],r2=a[2],r3=a[3],r4=a[4],r5=a[5],r6=a[6],r7=a[7];
  #pragma unroll
  for (int i = 8; i < 64; i += 8) {
    r0 += a[i+0]; r1 += a[i+1]; r2 += a[i+2]; r3 += a[i+3];
    r4 += a[i+4]; r5 += a[i+5]; r6 += a[i+6]; r7 += a[i+7];
  }
  return ((r0+r1)+(r2+r3))+((r4+r5)+(r6+r7));
}

// ---------------- stable row-sort (counting sort by chunk) ----------------
__global__ void k_chunkhist(const int* __restrict__ rows, uint32_t* __restrict__ cnt) {
  int i = blockIdx.x * blockDim.x + threadIdx.x;
  if (i >= NE) return;
  int c = i / CHSZ;
  atomicAdd(&cnt[(size_t)c * NN + (uint32_t)rows[i]], 1u);
}

__global__ void k_rowprefix(uint32_t* __restrict__ cnt, uint32_t* __restrict__ total) {
  int r = blockIdx.x * blockDim.x + threadIdx.x;
  if (r >= NN) return;
  uint32_t run = 0;
  for (int c = 0; c < NCHUNK; c++) {
    size_t idx = (size_t)c * NN + r;
    uint32_t t = cnt[idx]; cnt[idx] = run; run += t;
  }
  total[r] = run;
}

__global__ void k_scan1(const uint32_t* __restrict__ total, uint32_t* __restrict__ rstart,
                        uint32_t* __restrict__ bsum) {
  __shared__ uint32_t s[1024];
  int i = blockIdx.x * 1024 + threadIdx.x;
  uint32_t v = (i < NN) ? total[i] : 0u;
  s[threadIdx.x] = v; __syncthreads();
  for (int o = 1; o < 1024; o <<= 1) {
    uint32_t x = (threadIdx.x >= (unsigned)o) ? s[threadIdx.x - o] : 0u;
    __syncthreads();
    s[threadIdx.x] += x;
    __syncthreads();
  }
  if (i <= NN) rstart[i] = s[threadIdx.x] - v;
  if (threadIdx.x == 1023) bsum[blockIdx.x] = s[1023];
}

__global__ void k_scan2(uint32_t* __restrict__ bsum) {
  if (blockIdx.x == 0 && threadIdx.x == 0) {
    uint32_t run = 0;
    for (int b = 0; b < SCAN_BLOCKS; b++) { uint32_t t = bsum[b]; bsum[b] = run; run += t; }
  }
}

__global__ void k_scan3(uint32_t* __restrict__ rstart, const uint32_t* __restrict__ bsum) {
  int i = blockIdx.x * 1024 + threadIdx.x;
  if (i <= NN) rstart[i] += bsum[blockIdx.x];
}

// one wave per chunk; batches of 64 processed in order -> stable by edge index
__global__ void k_scatter(const int* __restrict__ rows, const int* __restrict__ cols,
                          const uint32_t* __restrict__ rstart, uint32_t* __restrict__ cnt,
                          uint32_t* __restrict__ scol, uint32_t* __restrict__ seid) {
  int c = blockIdx.x;
  int lane = threadIdx.x;
  uint32_t* basec = cnt + (size_t)c * NN;
  const int nb = (CHSZ + 63) / 64;
  for (int b = 0; b < nb; b++) {
    int off = b * 64 + lane;
    bool valid = off < CHSZ;
    uint32_t e = (uint32_t)c * CHSZ + (uint32_t)off;
    uint32_t r = valid ? (uint32_t)rows[e] : 0xFFFFFFFFu;
    unsigned long long eq = 0ULL;
    for (int j = 0; j < 64; j++) {
      uint32_t rj = (uint32_t)__shfl((int)r, j);
      eq |= ((unsigned long long)(rj == r)) << j;
    }
    unsigned long long lt = (1ULL << lane) - 1ULL;
    int rank = __popcll(eq & lt);
    int cn   = __popcll(eq);
    int leader = __ffsll((unsigned long long)eq) - 1;
    uint32_t old = 0;
    if (valid && lane == leader) old = atomicAdd(&basec[r], (uint32_t)cn);
    old = (uint32_t)__shfl((int)old, leader);
    if (valid) {
      uint32_t pos = rstart[r] + old + (uint32_t)rank;
      scol[pos] = (uint32_t)cols[e];
      seid[pos] = e;
    }
  }
}

// ---------------- masked value arrays (sorted order) ----------------
__global__ void k_maskvals(const uint32_t* __restrict__ seid, const float* __restrict__ vals,
                           float* __restrict__ v0s, float* __restrict__ vAs, float* __restrict__ vBs,
                           uint32_t kd0a, uint32_t kd0b, uint32_t kd1a, uint32_t kd1b) {
#pragma clang fp contract(off)
  int p = blockIdx.x * blockDim.x + threadIdx.x;
  if (p >= NE) return;
  uint32_t e = seid[p];
  float v = vals[e];
  float u0 = u01_from_key(kd0a, kd0b, e);
  float m0 = floorf(u0 + 0.5f);
  float u1 = u01_from_key(kd1a, kd1b, e);
  float m1 = floorf(u1 + 0.25f);
  float a  = v * m0;
  float b2 = a * m1;
  v0s[p] = v; vAs[p] = a; vBs[p] = b2;
}

// rowsum(vals0), rowsum(vals1) -- sequential in edge order (f32)
__global__ void k_rowsum(const uint32_t* __restrict__ rp, const float* __restrict__ v0s,
                         const float* __restrict__ vAs, float* __restrict__ order0,
                         float* __restrict__ order1) {
#pragma clang fp contract(off)
  int r = blockIdx.x * blockDim.x + threadIdx.x;
  if (r >= NN) return;
  uint32_t p0 = rp[r], p1 = rp[r + 1];
  float o0 = 0.0f, o1 = 0.0f;
  for (uint32_t p = p0; p < p1; p++) { o0 = o0 + v0s[p]; o1 = o1 + vAs[p]; }
  order0[r] = o0; order1[r] = o1;
}

// fst = spmm(vals0, embeds) - embeds ; esum = fst
__global__ void k_fst(const uint32_t* __restrict__ rp, const uint32_t* __restrict__ scol,
                      const float* __restrict__ v0s, const float* __restrict__ emb,
                      float* __restrict__ fst, float* __restrict__ esum) {
#pragma clang fp contract(off)
  int r = blockIdx.x; int d = threadIdx.x;
  uint32_t p0 = rp[r], p1 = rp[r + 1];
  float acc = 0.0f;
  for (uint32_t p = p0; p < p1; p++) {
    float v = v0s[p]; uint32_t c = scol[p];
    acc = acc + v * emb[(size_t)c * 64 + d];
  }
  float f = acc - emb[(size_t)r * 64 + d];
  fst[(size_t)r * 64 + d] = f;
  esum[(size_t)r * 64 + d] = f;
}

// num_new0 = spmm(vals1, order0) - order0 - order0 ; num_sum = order0 + num_new0
__global__ void k_numA(const uint32_t* __restrict__ rp, const uint32_t* __restrict__ scol,
                       const float* __restrict__ vAs, const float* __restrict__ order0,
                       float* __restrict__ num0, float* __restrict__ num_sum) {
#pragma clang fp contract(off)
  int r = blockIdx.x * blockDim.x + threadIdx.x;
  if (r >= NN) return;
  uint32_t p0 = rp[r], p1 = rp[r + 1];
  float acc = 0.0f;
  for (uint32_t p = p0; p < p1; p++) acc = acc + vAs[p] * order0[scol[p]];
  float o = order0[r];
  float n0 = (acc - o) - o;
  num0[r] = n0;
  num_sum[r] = o + n0;
}

// emb_new0 = spmm(vals1, fst) - fst - order0*fst ; esum += emb_new0
__global__ void k_emb1(const uint32_t* __restrict__ rp, const uint32_t* __restrict__ scol,
                       const float* __restrict__ vAs, const float* __restrict__ fst,
                       const float* __restrict__ order0, float* __restrict__ emb1,
                       float* __restrict__ esum) {
#pragma clang fp contract(off)
  int r = blockIdx.x; int d = threadIdx.x;
  uint32_t p0 = rp[r], p1 = rp[r + 1];
  float acc = 0.0f;
  for (uint32_t p = p0; p < p1; p++) {
    float v = vAs[p]; uint32_t c = scol[p];
    acc = acc + v * fst[(size_t)c * 64 + d];
  }
  size_t i = (size_t)r * 64 + d;
  float pr = fst[i];
  float t  = order0[r] * pr;
  float e1 = (acc - pr) - t;
  emb1[i] = e1;
  esum[i] = esum[i] + e1;
}

// num_new1 = spmm(vals2, num0) - num0 - order1 ; num_sum += num_new1
__global__ void k_numB(const uint32_t* __restrict__ rp, const uint32_t* __restrict__ scol,
                       const float* __restrict__ vBs, const float* __restrict__ num0,
                       const float* __restrict__ order1, float* __restrict__ num_sum) {
#pragma clang fp contract(off)
  int r = blockIdx.x * blockDim.x + threadIdx.x;
  if (r >= NN) return;
  uint32_t p0 = rp[r], p1 = rp[r + 1];
  float acc = 0.0f;
  for (uint32_t p = p0; p < p1; p++) acc = acc + vBs[p] * num0[scol[p]];
  float n1 = (acc - num0[r]) - order1[r];
  num_sum[r] = num_sum[r] + n1;
}

// emb_new1 = spmm(vals2, emb1) - emb1 - order1*emb1 ; esum += emb_new1
__global__ void k_emb2(const uint32_t* __restrict__ rp, const uint32_t* __restrict__ scol,
                       const float* __restrict__ vBs, const float* __restrict__ emb1,
                       const float* __restrict__ order1, float* __restrict__ esum) {
#pragma clang fp contract(off)
  int r = blockIdx.x; int d = threadIdx.x;
  uint32_t p0 = rp[r], p1 = rp[r + 1];
  float acc = 0.0f;
  for (uint32_t p = p0; p < p1; p++) {
    float v = vBs[p]; uint32_t c = scol[p];
    acc = acc + v * emb1[(size_t)c * 64 + d];
  }
  size_t i = (size_t)r * 64 + d;
  float pr = emb1[i];
  float t  = order1[r] * pr;
  float e2 = (acc - pr) - t;
  esum[i] = esum[i] + e2;
}

// scores = dot(l2norm(esum/(num_sum+1e-8)), l2norm(embeds)) + gumbel(kn)
// OUTPUT IS FLOAT32 (harness reads d_out as f32)
__global__ void k_scores(const float* __restrict__ esum, const float* __restrict__ num_sum,
                         const float* __restrict__ emb, uint32_t* __restrict__ m_arr,
                         float* __restrict__ out_scores, uint32_t kna, uint32_t knb) {
#pragma clang fp contract(off)
  int r = blockIdx.x * blockDim.x + threadIdx.x;
  if (r >= NN) return;
  float t[64], w[64];
  float denom = num_sum[r] + 1e-8f;
  #pragma unroll
  for (int d = 0; d < 64; d++) t[d] = esum[(size_t)r * 64 + d] / denom;
  #pragma unroll
  for (int d = 0; d < 64; d++) w[d] = t[d] * t[d];
  float nn = fmaxf(sqrtf(np_sum64(w)), 1e-12f);
  #pragma unroll
  for (int d = 0; d < 64; d++) t[d] = t[d] / nn;
  #pragma unroll
  for (int d = 0; d < 64; d++) { float e = emb[(size_t)r * 64 + d]; w[d] = e * e; }
  float mn = fmaxf(sqrtf(np_sum64(w)), 1e-12f);
  #pragma unroll
  for (int d = 0; d < 64; d++) {
    float e = emb[(size_t)r * 64 + d];
    w[d] = t[d] * (e / mn);
  }
  float s = np_sum64(w);
  // Gumbel noise with f32 intermediate rounding, logs via double (approx. correctly-rounded f32 log)
  float u  = u01_from_key(kna, knb, (uint32_t)r);
  float l1 = (float)log((double)u);
  float l2 = (float)log((double)(-l1));
  s = s + (-l2);
  uint32_t b = __float_as_uint(s);
  m_arr[r] = b ^ (uint32_t)(((int32_t)b >> 31) | (int32_t)0x80000000);
  out_scores[r] = s;
}

// ---------------- exact top-1024 selection ----------------
__global__ void k_topk_init(uint32_t* __restrict__ hist, uint32_t* __restrict__ sel,
                            uint32_t* __restrict__ ccnt) {
  int t = threadIdx.x;
  if (t < 256) hist[t] = 0;
  if (t == 0) { sel[0] = 0; sel[1] = NCAND; *ccnt = 0; }
}

__global__ void k_hist(const uint32_t* __restrict__ m_arr, uint32_t* __restrict__ hist,
                       const uint32_t* __restrict__ sel, int shift) {
  int i = blockIdx.x * blockDim.x + threadIdx.x;
  int stride = gridDim.x * blockDim.x;
  uint32_t pref = sel[0];
  for (; i < NN; i += stride) {
    uint32_t m = m_arr[i];
    bool ok = (shift == 24) || ((m >> (shift + 8)) == pref);
    if (ok) atomicAdd(&hist[(m >> shift) & 255u], 1u);
  }
}

__global__ void k_select(uint32_t* __restrict__ hist, uint32_t* __restrict__ sel) {
  if (threadIdx.x == 0) {
    uint32_t need = sel[1];
    uint32_t pref = sel[0];
    int b;
    for (b = 255; b > 0; b--) {
      uint32_t c = hist[b];
      if (c < need) need -= c; else break;
    }
    sel[0] = (pref << 8) | (uint32_t)b;
    sel[1] = need;
  }
  __syncthreads();
  if (threadIdx.x < 256) hist[threadIdx.x] = 0;
}

__global__ void k_collect(const uint32_t* __restrict__ m_arr, const uint32_t* __restrict__ sel,
                          unsigned long long* __restrict__ cbuf, uint32_t* __restrict__ ccnt) {
  int i = blockIdx.x * blockDim.x + threadIdx.x;
  int stride = gridDim.x * blockDim.x;
  uint32_t thr = sel[0];
  for (; i < NN; i += stride) {
    uint32_t m = m_arr[i];
    if (m >= thr) {
      uint32_t pos = atomicAdd(ccnt, 1u);
      if (pos < 4096)
        cbuf[pos] = ((unsigned long long)m << 32) | (uint32_t)(~(uint32_t)i);
    }
  }
}

// OUTPUT IS FLOAT32 (indices as f32)
__global__ void k_sortemit(const unsigned long long* __restrict__ cbuf,
                           const uint32_t* __restrict__ ccnt, float* __restrict__ out) {
  __shared__ unsigned long long s[4096];
  uint32_t n = *ccnt; if (n > 4096u) n = 4096u;
  for (int i = threadIdx.x; i < 4096; i += 1024) s[i] = (i < (int)n) ? cbuf[i] : 0ULL;
  __syncthreads();
  for (int k = 2; k <= 4096; k <<= 1) {
    for (int j = k >> 1; j > 0; j >>= 1) {
      for (int i = threadIdx.x; i < 4096; i += 1024) {
        int ixj = i ^ j;
        if (ixj > i) {
          bool up = ((i & k) == 0);
          unsigned long long a = s[i], b = s[ixj];
          if ((a > b) == up) { s[i] = b; s[ixj] = a; }
        }
      }
      __syncthreads();
    }
  }
  for (int j = threadIdx.x; j < NCAND; j += 1024) {
    unsigned long long key = s[4095 - j];
    uint32_t idx = ~(uint32_t)(key & 0xFFFFFFFFull);
    out[j] = (float)idx;
  }
}

// ---------------- launcher ----------------
extern "C" void kernel_launch(void* const* d_in, const int* in_sizes, int n_in,
                              void* d_out, int out_size, void* d_ws, size_t ws_size,
                              hipStream_t stream) {
  (void)in_sizes; (void)n_in; (void)out_size; (void)ws_size;
  const int*   rows = (const int*)d_in[0];
  const int*   cols = (const int*)d_in[1];
  const float* vals = (const float*)d_in[2];
  const float* emb  = (const float*)d_in[3];
  float* out = (float*)d_out;   // f32: scores[NN] then candidates[1024]

  // workspace carve (aligned 256B); total ~170 MB
  char* w = (char*)d_ws;
  auto alloc = [&](size_t bytes) -> void* {
    void* p = (void*)w; w += (bytes + 255) & ~(size_t)255; return p;
  };
  uint32_t* cnt     = (uint32_t*)alloc((size_t)NCHUNK * NN * 4);
  uint32_t* total   = (uint32_t*)alloc((size_t)NN * 4);
  uint32_t* rstart  = (uint32_t*)alloc((size_t)(NN + 1) * 4);
  uint32_t* bsum    = (uint32_t*)alloc((size_t)SCAN_BLOCKS * 4);
  uint32_t* scol    = (uint32_t*)alloc((size_t)NE * 4);
  uint32_t* seid    = (uint32_t*)alloc((size_t)NE * 4);
  float*    v0s     = (float*)alloc((size_t)NE * 4);
  float*    vAs     = (float*)alloc((size_t)NE * 4);
  float*    vBs     = (float*)alloc((size_t)NE * 4);
  float*    order0  = (float*)alloc((size_t)NN * 4);
  float*    order1  = (float*)alloc((size_t)NN * 4);
  float*    num0    = (float*)alloc((size_t)NN * 4);
  float*    num_sum = (float*)alloc((size_t)NN * 4);
  float*    fst     = (float*)alloc((size_t)NN * 64 * 4);
  float*    emb1    = (float*)alloc((size_t)NN * 64 * 4);
  float*    esum    = (float*)alloc((size_t)NN * 64 * 4);
  uint32_t* m_arr   = (uint32_t*)alloc((size_t)NN * 4);
  uint32_t* hist    = (uint32_t*)alloc(256 * 4);
  uint32_t* sel     = (uint32_t*)alloc(2 * 4);
  uint32_t* ccnt    = (uint32_t*)alloc(4);
  unsigned long long* cbuf = (unsigned long long*)alloc(4096 * 8);

  // host-side threefry key chain (data-independent):
  // key0=(0,42); key,kd = split(key) twice; key,kn = split(key)
  uint32_t K1a,K1b, kd0a,kd0b, K2a,K2b, kd1a,kd1b, kna,knb;
  tf2x32(0u, 42u, 0u, 0u, K1a, K1b);
  tf2x32(0u, 42u, 0u, 1u, kd0a, kd0b);
  tf2x32(K1a, K1b, 0u, 0u, K2a, K2b);
  tf2x32(K1a, K1b, 0u, 1u, kd1a, kd1b);
  tf2x32(K2a, K2b, 0u, 1u, kna, knb);

  hipMemsetAsync(cnt, 0, (size_t)NCHUNK * NN * 4, stream);

  const int TPB = 256;
  k_chunkhist<<<(NE + TPB - 1) / TPB, TPB, 0, stream>>>(rows, cnt);
  k_rowprefix<<<(NN + TPB - 1) / TPB, TPB, 0, stream>>>(cnt, total);
  k_scan1<<<SCAN_BLOCKS, 1024, 0, stream>>>(total, rstart, bsum);
  k_scan2<<<1, 1, 0, stream>>>(bsum);
  k_scan3<<<SCAN_BLOCKS, 1024, 0, stream>>>(rstart, bsum);
  k_scatter<<<NCHUNK, 64, 0, stream>>>(rows, cols, rstart, cnt, scol, seid);
  k_maskvals<<<(NE + TPB - 1) / TPB, TPB, 0, stream>>>(seid, vals, v0s, vAs, vBs,
                                                       kd0a, kd0b, kd1a, kd1b);
  k_rowsum<<<(NN + TPB - 1) / TPB, TPB, 0, stream>>>(rstart, v0s, vAs, order0, order1);
  k_fst<<<NN, 64, 0, stream>>>(rstart, scol, v0s, emb, fst, esum);
  k_numA<<<(NN + TPB - 1) / TPB, TPB, 0, stream>>>(rstart, scol, vAs, order0, num0, num_sum);
  k_emb1<<<NN, 64, 0, stream>>>(rstart, scol, vAs, fst, order0, emb1, esum);
  k_numB<<<(NN + TPB - 1) / TPB, TPB, 0, stream>>>(rstart, scol, vBs, num0, order1, num_sum);
  k_emb2<<<NN, 64, 0, stream>>>(rstart, scol, vBs, emb1, order1, esum);
  k_scores<<<(NN + TPB - 1) / TPB, TPB, 0, stream>>>(esum, num_sum, emb, m_arr, out, kna, knb);

  k_topk_init<<<1, 256, 0, stream>>>(hist, sel, ccnt);
  for (int shift = 24; shift >= 0; shift -= 8) {
    k_hist<<<256, 256, 0, stream>>>(m_arr, hist, sel, shift);
    k_select<<<1, 256, 0, stream>>>(hist, sel);
  }
  k_collect<<<256, 256, 0, stream>>>(m_arr, sel, cbuf, ccnt);
  k_sortemit<<<1, 1024, 0, stream>>>(cbuf, ccnt, out + NN);
}

// Round 3
// 1754.577 us; speedup vs baseline: 2.0476x; 2.0476x over previous
//
#include <hip/hip_runtime.h>
#include <hip/hip_bf16.h>
#include <stdint.h>
#include <stddef.h>

// Problem constants (fixed by the reference)
#define NN 100000          // nodes
#define NE 3200000         // edges
#define NCAND 1024
#define SCAN_BLOCKS 98     // ceil((NN+1)/1024)

// ---------------- threefry2x32, exact JAX lowering ----------------
__host__ __device__ inline void tf2x32(uint32_t k0, uint32_t k1,
                                       uint32_t x0, uint32_t x1,
                                       uint32_t& y0, uint32_t& y1) {
  uint32_t ks2 = k0 ^ k1 ^ 0x1BD11BDAu;
  x0 += k0; x1 += k1;
#define TFR(r) { x0 += x1; x1 = (x1 << (r)) | (x1 >> (32 - (r))); x1 ^= x0; }
  TFR(13) TFR(15) TFR(26) TFR(6)
  x0 += k1;  x1 += ks2 + 1u;
  TFR(17) TFR(29) TFR(16) TFR(24)
  x0 += ks2; x1 += k0 + 2u;
  TFR(13) TFR(15) TFR(26) TFR(6)
  x0 += k0;  x1 += k1 + 3u;
  TFR(17) TFR(29) TFR(16) TFR(24)
  x0 += k1;  x1 += ks2 + 4u;
  TFR(13) TFR(15) TFR(26) TFR(6)
  x0 += ks2; x1 += k0 + 5u;
#undef TFR
  y0 = x0; y1 = x1;
}

// partitionable random_bits(key,32,(n,)): element i -> y0^y1 of tf(key,(0,i));
// uniform: bitcast((bits>>9)|0x3F800000) - 1
__device__ inline float u01_from_key(uint32_t ka, uint32_t kb, uint32_t idx) {
  uint32_t y0, y1; tf2x32(ka, kb, 0u, idx, y0, y1);
  uint32_t bits = y0 ^ y1;
  return __uint_as_float((bits >> 9) | 0x3F800000u) - 1.0f;
}

// numpy pairwise sum for 64 contiguous f32 (8 accumulators + tree combine)
__device__ inline float np_sum64(const float* a) {
#pragma clang fp contract(off)
  float r0=a[0],r1=a[1],r2=a[2],r3=a[3],r4=a[4],r5=a[5],r6=a[6],r7=a[7];
  #pragma unroll
  for (int i = 8; i < 64; i += 8) {
    r0 += a[i+0]; r1 += a[i+1]; r2 += a[i+2]; r3 += a[i+3];
    r4 += a[i+4]; r5 += a[i+5]; r6 += a[i+6]; r7 += a[i+7];
  }
  return ((r0+r1)+(r2+r3))+((r4+r5)+(r6+r7));
}

// ---------------- stable row-grouping (parallel) ----------------
// total[r] counts, then scan -> rstart; scatter with per-row atomic cursor
// (unordered), then per-row insertion sort of edge ids restores edge order.
__global__ void k_histrows(const int* __restrict__ rows, uint32_t* __restrict__ total) {
  int i = blockIdx.x * blockDim.x + threadIdx.x;
  if (i >= NE) return;
  atomicAdd(&total[(uint32_t)rows[i]], 1u);
}

__global__ void k_scan1(const uint32_t* __restrict__ total, uint32_t* __restrict__ rstart,
                        uint32_t* __restrict__ bsum) {
  __shared__ uint32_t s[1024];
  int i = blockIdx.x * 1024 + threadIdx.x;
  uint32_t v = (i < NN) ? total[i] : 0u;
  s[threadIdx.x] = v; __syncthreads();
  for (int o = 1; o < 1024; o <<= 1) {
    uint32_t x = (threadIdx.x >= (unsigned)o) ? s[threadIdx.x - o] : 0u;
    __syncthreads();
    s[threadIdx.x] += x;
    __syncthreads();
  }
  if (i <= NN) rstart[i] = s[threadIdx.x] - v;
  if (threadIdx.x == 1023) bsum[blockIdx.x] = s[1023];
}

__global__ void k_scan2(uint32_t* __restrict__ bsum) {
  if (blockIdx.x == 0 && threadIdx.x == 0) {
    uint32_t run = 0;
    for (int b = 0; b < SCAN_BLOCKS; b++) { uint32_t t = bsum[b]; bsum[b] = run; run += t; }
  }
}

__global__ void k_scan3(uint32_t* __restrict__ rstart, const uint32_t* __restrict__ bsum) {
  int i = blockIdx.x * 1024 + threadIdx.x;
  if (i <= NN) rstart[i] += bsum[blockIdx.x];
}

__global__ void k_scatter2(const int* __restrict__ rows, const uint32_t* __restrict__ rstart,
                           uint32_t* __restrict__ cursor, uint32_t* __restrict__ seid) {
  int i = blockIdx.x * blockDim.x + threadIdx.x;
  if (i >= NE) return;
  uint32_t r = (uint32_t)rows[i];
  uint32_t pos = rstart[r] + atomicAdd(&cursor[r], 1u);
  seid[pos] = (uint32_t)i;
}

// one thread per row: insertion sort of the row's edge ids (avg 32, contiguous)
__global__ void k_rowsort(const uint32_t* __restrict__ rp, uint32_t* __restrict__ seid) {
  int r = blockIdx.x * blockDim.x + threadIdx.x;
  if (r >= NN) return;
  uint32_t p0 = rp[r], p1 = rp[r + 1];
  for (uint32_t i = p0 + 1; i < p1; i++) {
    uint32_t key = seid[i];
    uint32_t j = i;
    while (j > p0 && seid[j - 1] > key) { seid[j] = seid[j - 1]; j--; }
    seid[j] = key;
  }
}

// ---------------- masked value arrays (sorted order) + column gather --------
__global__ void k_maskvals(const uint32_t* __restrict__ seid, const int* __restrict__ cols,
                           const float* __restrict__ vals,
                           uint32_t* __restrict__ scol,
                           float* __restrict__ v0s, float* __restrict__ vAs, float* __restrict__ vBs,
                           uint32_t kd0a, uint32_t kd0b, uint32_t kd1a, uint32_t kd1b) {
#pragma clang fp contract(off)
  int p = blockIdx.x * blockDim.x + threadIdx.x;
  if (p >= NE) return;
  uint32_t e = seid[p];
  float v = vals[e];
  scol[p] = (uint32_t)cols[e];
  float u0 = u01_from_key(kd0a, kd0b, e);
  float m0 = floorf(u0 + 0.5f);
  float u1 = u01_from_key(kd1a, kd1b, e);
  float m1 = floorf(u1 + 0.25f);
  float a  = v * m0;
  float b2 = a * m1;
  v0s[p] = v; vAs[p] = a; vBs[p] = b2;
}

// rowsum(vals0), rowsum(vals1) -- sequential in edge order (f32)
__global__ void k_rowsum(const uint32_t* __restrict__ rp, const float* __restrict__ v0s,
                         const float* __restrict__ vAs, float* __restrict__ order0,
                         float* __restrict__ order1) {
#pragma clang fp contract(off)
  int r = blockIdx.x * blockDim.x + threadIdx.x;
  if (r >= NN) return;
  uint32_t p0 = rp[r], p1 = rp[r + 1];
  float o0 = 0.0f, o1 = 0.0f;
  for (uint32_t p = p0; p < p1; p++) { o0 = o0 + v0s[p]; o1 = o1 + vAs[p]; }
  order0[r] = o0; order1[r] = o1;
}

// fst = spmm(vals0, embeds) - embeds ; esum = fst
__global__ void k_fst(const uint32_t* __restrict__ rp, const uint32_t* __restrict__ scol,
                      const float* __restrict__ v0s, const float* __restrict__ emb,
                      float* __restrict__ fst, float* __restrict__ esum) {
#pragma clang fp contract(off)
  int r = blockIdx.x; int d = threadIdx.x;
  uint32_t p0 = rp[r], p1 = rp[r + 1];
  float acc = 0.0f;
  for (uint32_t p = p0; p < p1; p++) {
    float v = v0s[p]; uint32_t c = scol[p];
    acc = acc + v * emb[(size_t)c * 64 + d];
  }
  float f = acc - emb[(size_t)r * 64 + d];
  fst[(size_t)r * 64 + d] = f;
  esum[(size_t)r * 64 + d] = f;
}

// num_new0 = spmm(vals1, order0) - order0 - order0 ; num_sum = order0 + num_new0
__global__ void k_numA(const uint32_t* __restrict__ rp, const uint32_t* __restrict__ scol,
                       const float* __restrict__ vAs, const float* __restrict__ order0,
                       float* __restrict__ num0, float* __restrict__ num_sum) {
#pragma clang fp contract(off)
  int r = blockIdx.x * blockDim.x + threadIdx.x;
  if (r >= NN) return;
  uint32_t p0 = rp[r], p1 = rp[r + 1];
  float acc = 0.0f;
  for (uint32_t p = p0; p < p1; p++) acc = acc + vAs[p] * order0[scol[p]];
  float o = order0[r];
  float n0 = (acc - o) - o;
  num0[r] = n0;
  num_sum[r] = o + n0;
}

// emb_new0 = spmm(vals1, fst) - fst - order0*fst ; esum += emb_new0
__global__ void k_emb1(const uint32_t* __restrict__ rp, const uint32_t* __restrict__ scol,
                       const float* __restrict__ vAs, const float* __restrict__ fst,
                       const float* __restrict__ order0, float* __restrict__ emb1,
                       float* __restrict__ esum) {
#pragma clang fp contract(off)
  int r = blockIdx.x; int d = threadIdx.x;
  uint32_t p0 = rp[r], p1 = rp[r + 1];
  float acc = 0.0f;
  for (uint32_t p = p0; p < p1; p++) {
    float v = vAs[p]; uint32_t c = scol[p];
    acc = acc + v * fst[(size_t)c * 64 + d];
  }
  size_t i = (size_t)r * 64 + d;
  float pr = fst[i];
  float t  = order0[r] * pr;
  float e1 = (acc - pr) - t;
  emb1[i] = e1;
  esum[i] = esum[i] + e1;
}

// num_new1 = spmm(vals2, num0) - num0 - order1 ; num_sum += num_new1
__global__ void k_numB(const uint32_t* __restrict__ rp, const uint32_t* __restrict__ scol,
                       const float* __restrict__ vBs, const float* __restrict__ num0,
                       const float* __restrict__ order1, float* __restrict__ num_sum) {
#pragma clang fp contract(off)
  int r = blockIdx.x * blockDim.x + threadIdx.x;
  if (r >= NN) return;
  uint32_t p0 = rp[r], p1 = rp[r + 1];
  float acc = 0.0f;
  for (uint32_t p = p0; p < p1; p++) acc = acc + vBs[p] * num0[scol[p]];
  float n1 = (acc - num0[r]) - order1[r];
  num_sum[r] = num_sum[r] + n1;
}

// emb_new1 = spmm(vals2, emb1) - emb1 - order1*emb1 ; esum += emb_new1
__global__ void k_emb2(const uint32_t* __restrict__ rp, const uint32_t* __restrict__ scol,
                       const float* __restrict__ vBs, const float* __restrict__ emb1,
                       const float* __restrict__ order1, float* __restrict__ esum) {
#pragma clang fp contract(off)
  int r = blockIdx.x; int d = threadIdx.x;
  uint32_t p0 = rp[r], p1 = rp[r + 1];
  float acc = 0.0f;
  for (uint32_t p = p0; p < p1; p++) {
    float v = vBs[p]; uint32_t c = scol[p];
    acc = acc + v * emb1[(size_t)c * 64 + d];
  }
  size_t i = (size_t)r * 64 + d;
  float pr = emb1[i];
  float t  = order1[r] * pr;
  float e2 = (acc - pr) - t;
  esum[i] = esum[i] + e2;
}

// scores = dot(l2norm(esum/(num_sum+1e-8)), l2norm(embeds)) + gumbel(kn)
// OUTPUT IS FLOAT32 (harness reads d_out as f32)
__global__ void k_scores(const float* __restrict__ esum, const float* __restrict__ num_sum,
                         const float* __restrict__ emb, uint32_t* __restrict__ m_arr,
                         float* __restrict__ out_scores, uint32_t kna, uint32_t knb) {
#pragma clang fp contract(off)
  int r = blockIdx.x * blockDim.x + threadIdx.x;
  if (r >= NN) return;
  float t[64], w[64];
  float denom = num_sum[r] + 1e-8f;
  #pragma unroll
  for (int d = 0; d < 64; d++) t[d] = esum[(size_t)r * 64 + d] / denom;
  #pragma unroll
  for (int d = 0; d < 64; d++) w[d] = t[d] * t[d];
  float nn = fmaxf(sqrtf(np_sum64(w)), 1e-12f);
  #pragma unroll
  for (int d = 0; d < 64; d++) t[d] = t[d] / nn;
  #pragma unroll
  for (int d = 0; d < 64; d++) { float e = emb[(size_t)r * 64 + d]; w[d] = e * e; }
  float mn = fmaxf(sqrtf(np_sum64(w)), 1e-12f);
  #pragma unroll
  for (int d = 0; d < 64; d++) {
    float e = emb[(size_t)r * 64 + d];
    w[d] = t[d] * (e / mn);
  }
  float s = np_sum64(w);
  // Gumbel noise with f32 intermediate rounding, logs via double (approx. correctly-rounded f32 log)
  float u  = u01_from_key(kna, knb, (uint32_t)r);
  float l1 = (float)log((double)u);
  float l2 = (float)log((double)(-l1));
  s = s + (-l2);
  uint32_t b = __float_as_uint(s);
  m_arr[r] = b ^ (uint32_t)(((int32_t)b >> 31) | (int32_t)0x80000000);
  out_scores[r] = s;
}

// ---------------- exact top-1024 selection ----------------
__global__ void k_topk_init(uint32_t* __restrict__ hist, uint32_t* __restrict__ sel,
                            uint32_t* __restrict__ ccnt) {
  int t = threadIdx.x;
  if (t < 256) hist[t] = 0;
  if (t == 0) { sel[0] = 0; sel[1] = NCAND; *ccnt = 0; }
}

__global__ void k_hist(const uint32_t* __restrict__ m_arr, uint32_t* __restrict__ hist,
                       const uint32_t* __restrict__ sel, int shift) {
  int i = blockIdx.x * blockDim.x + threadIdx.x;
  int stride = gridDim.x * blockDim.x;
  uint32_t pref = sel[0];
  for (; i < NN; i += stride) {
    uint32_t m = m_arr[i];
    bool ok = (shift == 24) || ((m >> (shift + 8)) == pref);
    if (ok) atomicAdd(&hist[(m >> shift) & 255u], 1u);
  }
}

__global__ void k_select(uint32_t* __restrict__ hist, uint32_t* __restrict__ sel) {
  if (threadIdx.x == 0) {
    uint32_t need = sel[1];
    uint32_t pref = sel[0];
    int b;
    for (b = 255; b > 0; b--) {
      uint32_t c = hist[b];
      if (c < need) need -= c; else break;
    }
    sel[0] = (pref << 8) | (uint32_t)b;
    sel[1] = need;
  }
  __syncthreads();
  if (threadIdx.x < 256) hist[threadIdx.x] = 0;
}

__global__ void k_collect(const uint32_t* __restrict__ m_arr, const uint32_t* __restrict__ sel,
                          unsigned long long* __restrict__ cbuf, uint32_t* __restrict__ ccnt) {
  int i = blockIdx.x * blockDim.x + threadIdx.x;
  int stride = gridDim.x * blockDim.x;
  uint32_t thr = sel[0];
  for (; i < NN; i += stride) {
    uint32_t m = m_arr[i];
    if (m >= thr) {
      uint32_t pos = atomicAdd(ccnt, 1u);
      if (pos < 4096)
        cbuf[pos] = ((unsigned long long)m << 32) | (uint32_t)(~(uint32_t)i);
    }
  }
}

// OUTPUT IS FLOAT32 (indices as f32)
__global__ void k_sortemit(const unsigned long long* __restrict__ cbuf,
                           const uint32_t* __restrict__ ccnt, float* __restrict__ out) {
  __shared__ unsigned long long s[4096];
  uint32_t n = *ccnt; if (n > 4096u) n = 4096u;
  for (int i = threadIdx.x; i < 4096; i += 1024) s[i] = (i < (int)n) ? cbuf[i] : 0ULL;
  __syncthreads();
  for (int k = 2; k <= 4096; k <<= 1) {
    for (int j = k >> 1; j > 0; j >>= 1) {
      for (int i = threadIdx.x; i < 4096; i += 1024) {
        int ixj = i ^ j;
        if (ixj > i) {
          bool up = ((i & k) == 0);
          unsigned long long a = s[i], b = s[ixj];
          if ((a > b) == up) { s[i] = b; s[ixj] = a; }
        }
      }
      __syncthreads();
    }
  }
  for (int j = threadIdx.x; j < NCAND; j += 1024) {
    unsigned long long key = s[4095 - j];
    uint32_t idx = ~(uint32_t)(key & 0xFFFFFFFFull);
    out[j] = (float)idx;
  }
}

// ---------------- launcher ----------------
extern "C" void kernel_launch(void* const* d_in, const int* in_sizes, int n_in,
                              void* d_out, int out_size, void* d_ws, size_t ws_size,
                              hipStream_t stream) {
  (void)in_sizes; (void)n_in; (void)out_size; (void)ws_size;
  const int*   rows = (const int*)d_in[0];
  const int*   cols = (const int*)d_in[1];
  const float* vals = (const float*)d_in[2];
  const float* emb  = (const float*)d_in[3];
  float* out = (float*)d_out;   // f32: scores[NN] then candidates[1024]

  // workspace carve (aligned 256B); total ~145 MB
  char* w = (char*)d_ws;
  auto alloc = [&](size_t bytes) -> void* {
    void* p = (void*)w; w += (bytes + 255) & ~(size_t)255; return p;
  };
  uint32_t* total   = (uint32_t*)alloc((size_t)NN * 4);   // adjacent: one memset
  uint32_t* cursor  = (uint32_t*)alloc((size_t)NN * 4);   // covers both
  uint32_t* rstart  = (uint32_t*)alloc((size_t)(NN + 1) * 4);
  uint32_t* bsum    = (uint32_t*)alloc((size_t)SCAN_BLOCKS * 4);
  uint32_t* scol    = (uint32_t*)alloc((size_t)NE * 4);
  uint32_t* seid    = (uint32_t*)alloc((size_t)NE * 4);
  float*    v0s     = (float*)alloc((size_t)NE * 4);
  float*    vAs     = (float*)alloc((size_t)NE * 4);
  float*    vBs     = (float*)alloc((size_t)NE * 4);
  float*    order0  = (float*)alloc((size_t)NN * 4);
  float*    order1  = (float*)alloc((size_t)NN * 4);
  float*    num0    = (float*)alloc((size_t)NN * 4);
  float*    num_sum = (float*)alloc((size_t)NN * 4);
  float*    fst     = (float*)alloc((size_t)NN * 64 * 4);
  float*    emb1    = (float*)alloc((size_t)NN * 64 * 4);
  float*    esum    = (float*)alloc((size_t)NN * 64 * 4);
  uint32_t* m_arr   = (uint32_t*)alloc((size_t)NN * 4);
  uint32_t* hist    = (uint32_t*)alloc(256 * 4);
  uint32_t* sel     = (uint32_t*)alloc(2 * 4);
  uint32_t* ccnt    = (uint32_t*)alloc(4);
  unsigned long long* cbuf = (unsigned long long*)alloc(4096 * 8);

  // host-side threefry key chain (data-independent):
  // key0=(0,42); key,kd = split(key) twice; key,kn = split(key)
  uint32_t K1a,K1b, kd0a,kd0b, K2a,K2b, kd1a,kd1b, kna,knb;
  tf2x32(0u, 42u, 0u, 0u, K1a, K1b);
  tf2x32(0u, 42u, 0u, 1u, kd0a, kd0b);
  tf2x32(K1a, K1b, 0u, 0u, K2a, K2b);
  tf2x32(K1a, K1b, 0u, 1u, kd1a, kd1b);
  tf2x32(K2a, K2b, 0u, 1u, kna, knb);

  // zero total + cursor (adjacent allocations, padded to 256B each)
  hipMemsetAsync(total, 0, ((size_t)NN * 4 + 255 & ~(size_t)255) * 2, stream);

  const int TPB = 256;
  k_histrows<<<(NE + TPB - 1) / TPB, TPB, 0, stream>>>(rows, total);
  k_scan1<<<SCAN_BLOCKS, 1024, 0, stream>>>(total, rstart, bsum);
  k_scan2<<<1, 1, 0, stream>>>(bsum);
  k_scan3<<<SCAN_BLOCKS, 1024, 0, stream>>>(rstart, bsum);
  k_scatter2<<<(NE + TPB - 1) / TPB, TPB, 0, stream>>>(rows, rstart, cursor, seid);
  k_rowsort<<<(NN + TPB - 1) / TPB, TPB, 0, stream>>>(rstart, seid);
  k_maskvals<<<(NE + TPB - 1) / TPB, TPB, 0, stream>>>(seid, cols, vals, scol, v0s, vAs, vBs,
                                                       kd0a, kd0b, kd1a, kd1b);
  k_rowsum<<<(NN + TPB - 1) / TPB, TPB, 0, stream>>>(rstart, v0s, vAs, order0, order1);
  k_fst<<<NN, 64, 0, stream>>>(rstart, scol, v0s, emb, fst, esum);
  k_numA<<<(NN + TPB - 1) / TPB, TPB, 0, stream>>>(rstart, scol, vAs, order0, num0, num_sum);
  k_emb1<<<NN, 64, 0, stream>>>(rstart, scol, vAs, fst, order0, emb1, esum);
  k_numB<<<(NN + TPB - 1) / TPB, TPB, 0, stream>>>(rstart, scol, vBs, num0, order1, num_sum);
  k_emb2<<<NN, 64, 0, stream>>>(rstart, scol, vBs, emb1, order1, esum);
  k_scores<<<(NN + TPB - 1) / TPB, TPB, 0, stream>>>(esum, num_sum, emb, m_arr, out, kna, knb);

  k_topk_init<<<1, 256, 0, stream>>>(hist, sel, ccnt);
  for (int shift = 24; shift >= 0; shift -= 8) {
    k_hist<<<256, 256, 0, stream>>>(m_arr, hist, sel, shift);
    k_select<<<1, 256, 0, stream>>>(hist, sel);
  }
  k_collect<<<256, 256, 0, stream>>>(m_arr, sel, cbuf, ccnt);
  k_sortemit<<<1, 1024, 0, stream>>>(cbuf, ccnt, out + NN);
}

// Round 4
// 1393.717 us; speedup vs baseline: 2.5777x; 1.2589x over previous
//
#include <hip/hip_runtime.h>
#include <hip/hip_bf16.h>
#include <stdint.h>
#include <stddef.h>

// Problem constants (fixed by the reference)
#define NN 100000          // nodes
#define NE 3200000         // edges
#define NCAND 1024
#define SCAN_BLOCKS 98     // ceil((NN+1)/1024)

// ---------------- threefry2x32, exact JAX lowering ----------------
__host__ __device__ inline void tf2x32(uint32_t k0, uint32_t k1,
                                       uint32_t x0, uint32_t x1,
                                       uint32_t& y0, uint32_t& y1) {
  uint32_t ks2 = k0 ^ k1 ^ 0x1BD11BDAu;
  x0 += k0; x1 += k1;
#define TFR(r) { x0 += x1; x1 = (x1 << (r)) | (x1 >> (32 - (r))); x1 ^= x0; }
  TFR(13) TFR(15) TFR(26) TFR(6)
  x0 += k1;  x1 += ks2 + 1u;
  TFR(17) TFR(29) TFR(16) TFR(24)
  x0 += ks2; x1 += k0 + 2u;
  TFR(13) TFR(15) TFR(26) TFR(6)
  x0 += k0;  x1 += k1 + 3u;
  TFR(17) TFR(29) TFR(16) TFR(24)
  x0 += k1;  x1 += ks2 + 4u;
  TFR(13) TFR(15) TFR(26) TFR(6)
  x0 += ks2; x1 += k0 + 5u;
#undef TFR
  y0 = x0; y1 = x1;
}

// partitionable random_bits(key,32,(n,)): element i -> y0^y1 of tf(key,(0,i));
// uniform: bitcast((bits>>9)|0x3F800000) - 1
__device__ inline float u01_from_key(uint32_t ka, uint32_t kb, uint32_t idx) {
  uint32_t y0, y1; tf2x32(ka, kb, 0u, idx, y0, y1);
  uint32_t bits = y0 ^ y1;
  return __uint_as_float((bits >> 9) | 0x3F800000u) - 1.0f;
}

// numpy pairwise sum for 64 contiguous f32 (8 accumulators + tree combine)
__device__ inline float np_sum64(const float* a) {
#pragma clang fp contract(off)
  float r0=a[0],r1=a[1],r2=a[2],r3=a[3],r4=a[4],r5=a[5],r6=a[6],r7=a[7];
  #pragma unroll
  for (int i = 8; i < 64; i += 8) {
    r0 += a[i+0]; r1 += a[i+1]; r2 += a[i+2]; r3 += a[i+3];
    r4 += a[i+4]; r5 += a[i+5]; r6 += a[i+6]; r7 += a[i+7];
  }
  return ((r0+r1)+(r2+r3))+((r4+r5)+(r6+r7));
}

// ---------------- stable row-grouping (parallel) ----------------
__global__ void k_histrows(const int* __restrict__ rows, uint32_t* __restrict__ total) {
  int i = blockIdx.x * blockDim.x + threadIdx.x;
  if (i >= NE) return;
  atomicAdd(&total[(uint32_t)rows[i]], 1u);
}

__global__ void k_scan1(const uint32_t* __restrict__ total, uint32_t* __restrict__ rstart,
                        uint32_t* __restrict__ bsum) {
  __shared__ uint32_t s[1024];
  int i = blockIdx.x * 1024 + threadIdx.x;
  uint32_t v = (i < NN) ? total[i] : 0u;
  s[threadIdx.x] = v; __syncthreads();
  for (int o = 1; o < 1024; o <<= 1) {
    uint32_t x = (threadIdx.x >= (unsigned)o) ? s[threadIdx.x - o] : 0u;
    __syncthreads();
    s[threadIdx.x] += x;
    __syncthreads();
  }
  if (i <= NN) rstart[i] = s[threadIdx.x] - v;
  if (threadIdx.x == 1023) bsum[blockIdx.x] = s[1023];
}

__global__ void k_scan2(uint32_t* __restrict__ bsum) {
  if (blockIdx.x == 0 && threadIdx.x == 0) {
    uint32_t run = 0;
    for (int b = 0; b < SCAN_BLOCKS; b++) { uint32_t t = bsum[b]; bsum[b] = run; run += t; }
  }
}

__global__ void k_scan3(uint32_t* __restrict__ rstart, const uint32_t* __restrict__ bsum) {
  int i = blockIdx.x * 1024 + threadIdx.x;
  if (i <= NN) rstart[i] += bsum[blockIdx.x];
}

__global__ void k_scatter2(const int* __restrict__ rows, const uint32_t* __restrict__ rstart,
                           uint32_t* __restrict__ cursor, uint32_t* __restrict__ seid) {
  int i = blockIdx.x * blockDim.x + threadIdx.x;
  if (i >= NE) return;
  uint32_t r = (uint32_t)rows[i];
  uint32_t pos = rstart[r] + atomicAdd(&cursor[r], 1u);
  seid[pos] = (uint32_t)i;
}

// one thread per row: insertion sort of the row's edge ids (avg 32, contiguous)
__global__ void k_rowsort(const uint32_t* __restrict__ rp, uint32_t* __restrict__ seid) {
  int r = blockIdx.x * blockDim.x + threadIdx.x;
  if (r >= NN) return;
  uint32_t p0 = rp[r], p1 = rp[r + 1];
  for (uint32_t i = p0 + 1; i < p1; i++) {
    uint32_t key = seid[i];
    uint32_t j = i;
    while (j > p0 && seid[j - 1] > key) { seid[j] = seid[j - 1]; j--; }
    seid[j] = key;
  }
}

// ---------------- masked value arrays (sorted order) + column gather --------
__global__ void k_maskvals(const uint32_t* __restrict__ seid, const int* __restrict__ cols,
                           const float* __restrict__ vals,
                           uint32_t* __restrict__ scol,
                           float* __restrict__ v0s, float* __restrict__ vAs, float* __restrict__ vBs,
                           uint32_t kd0a, uint32_t kd0b, uint32_t kd1a, uint32_t kd1b) {
#pragma clang fp contract(off)
  int p = blockIdx.x * blockDim.x + threadIdx.x;
  if (p >= NE) return;
  uint32_t e = seid[p];
  float v = vals[e];
  scol[p] = (uint32_t)cols[e];
  float u0 = u01_from_key(kd0a, kd0b, e);
  float m0 = floorf(u0 + 0.5f);
  float u1 = u01_from_key(kd1a, kd1b, e);
  float m1 = floorf(u1 + 0.25f);
  float a  = v * m0;
  float b2 = a * m1;
  v0s[p] = v; vAs[p] = a; vBs[p] = b2;
}

// rowsum(vals0), rowsum(vals1) -- sequential in edge order (f32)
__global__ void k_rowsum(const uint32_t* __restrict__ rp, const float* __restrict__ v0s,
                         const float* __restrict__ vAs, float* __restrict__ order0,
                         float* __restrict__ order1) {
#pragma clang fp contract(off)
  int r = blockIdx.x * blockDim.x + threadIdx.x;
  if (r >= NN) return;
  uint32_t p0 = rp[r], p1 = rp[r + 1];
  float o0 = 0.0f, o1 = 0.0f;
  for (uint32_t p = p0; p < p1; p++) { o0 = o0 + v0s[p]; o1 = o1 + vAs[p]; }
  order0[r] = o0; order1[r] = o1;
}

// fst = spmm(vals0, embeds) - embeds ; esum = fst
__global__ void k_fst(const uint32_t* __restrict__ rp, const uint32_t* __restrict__ scol,
                      const float* __restrict__ v0s, const float* __restrict__ emb,
                      float* __restrict__ fst, float* __restrict__ esum) {
#pragma clang fp contract(off)
  int r = blockIdx.x; int d = threadIdx.x;
  uint32_t p0 = rp[r], p1 = rp[r + 1];
  float acc = 0.0f;
  for (uint32_t p = p0; p < p1; p++) {
    float v = v0s[p]; uint32_t c = scol[p];
    acc = acc + v * emb[(size_t)c * 64 + d];
  }
  float f = acc - emb[(size_t)r * 64 + d];
  fst[(size_t)r * 64 + d] = f;
  esum[(size_t)r * 64 + d] = f;
}

// num_new0 = spmm(vals1, order0) - order0 - order0 ; num_sum = order0 + num_new0
__global__ void k_numA(const uint32_t* __restrict__ rp, const uint32_t* __restrict__ scol,
                       const float* __restrict__ vAs, const float* __restrict__ order0,
                       float* __restrict__ num0, float* __restrict__ num_sum) {
#pragma clang fp contract(off)
  int r = blockIdx.x * blockDim.x + threadIdx.x;
  if (r >= NN) return;
  uint32_t p0 = rp[r], p1 = rp[r + 1];
  float acc = 0.0f;
  for (uint32_t p = p0; p < p1; p++) acc = acc + vAs[p] * order0[scol[p]];
  float o = order0[r];
  float n0 = (acc - o) - o;
  num0[r] = n0;
  num_sum[r] = o + n0;
}

// emb_new0 = spmm(vals1, fst) - fst - order0*fst ; esum += emb_new0
__global__ void k_emb1(const uint32_t* __restrict__ rp, const uint32_t* __restrict__ scol,
                       const float* __restrict__ vAs, const float* __restrict__ fst,
                       const float* __restrict__ order0, float* __restrict__ emb1,
                       float* __restrict__ esum) {
#pragma clang fp contract(off)
  int r = blockIdx.x; int d = threadIdx.x;
  uint32_t p0 = rp[r], p1 = rp[r + 1];
  float acc = 0.0f;
  for (uint32_t p = p0; p < p1; p++) {
    float v = vAs[p]; uint32_t c = scol[p];
    acc = acc + v * fst[(size_t)c * 64 + d];
  }
  size_t i = (size_t)r * 64 + d;
  float pr = fst[i];
  float t  = order0[r] * pr;
  float e1 = (acc - pr) - t;
  emb1[i] = e1;
  esum[i] = esum[i] + e1;
}

// num_new1 = spmm(vals2, num0) - num0 - order1 ; num_sum += num_new1
__global__ void k_numB(const uint32_t* __restrict__ rp, const uint32_t* __restrict__ scol,
                       const float* __restrict__ vBs, const float* __restrict__ num0,
                       const float* __restrict__ order1, float* __restrict__ num_sum) {
#pragma clang fp contract(off)
  int r = blockIdx.x * blockDim.x + threadIdx.x;
  if (r >= NN) return;
  uint32_t p0 = rp[r], p1 = rp[r + 1];
  float acc = 0.0f;
  for (uint32_t p = p0; p < p1; p++) acc = acc + vBs[p] * num0[scol[p]];
  float n1 = (acc - num0[r]) - order1[r];
  num_sum[r] = num_sum[r] + n1;
}

// emb_new1 = spmm(vals2, emb1) - emb1 - order1*emb1 ; esum += emb_new1
__global__ void k_emb2(const uint32_t* __restrict__ rp, const uint32_t* __restrict__ scol,
                       const float* __restrict__ vBs, const float* __restrict__ emb1,
                       const float* __restrict__ order1, float* __restrict__ esum) {
#pragma clang fp contract(off)
  int r = blockIdx.x; int d = threadIdx.x;
  uint32_t p0 = rp[r], p1 = rp[r + 1];
  float acc = 0.0f;
  for (uint32_t p = p0; p < p1; p++) {
    float v = vBs[p]; uint32_t c = scol[p];
    acc = acc + v * emb1[(size_t)c * 64 + d];
  }
  size_t i = (size_t)r * 64 + d;
  float pr = emb1[i];
  float t  = order1[r] * pr;
  float e2 = (acc - pr) - t;
  esum[i] = esum[i] + e2;
}

// scores = dot(l2norm(esum/(num_sum+1e-8)), l2norm(embeds)) + gumbel(kn)
// OUTPUT IS FLOAT32 (harness reads d_out as f32)
__global__ void k_scores(const float* __restrict__ esum, const float* __restrict__ num_sum,
                         const float* __restrict__ emb, uint32_t* __restrict__ m_arr,
                         float* __restrict__ out_scores, uint32_t kna, uint32_t knb) {
#pragma clang fp contract(off)
  int r = blockIdx.x * blockDim.x + threadIdx.x;
  if (r >= NN) return;
  float t[64], w[64];
  float denom = num_sum[r] + 1e-8f;
  #pragma unroll
  for (int d = 0; d < 64; d++) t[d] = esum[(size_t)r * 64 + d] / denom;
  #pragma unroll
  for (int d = 0; d < 64; d++) w[d] = t[d] * t[d];
  float nn = fmaxf(sqrtf(np_sum64(w)), 1e-12f);
  #pragma unroll
  for (int d = 0; d < 64; d++) t[d] = t[d] / nn;
  #pragma unroll
  for (int d = 0; d < 64; d++) { float e = emb[(size_t)r * 64 + d]; w[d] = e * e; }
  float mn = fmaxf(sqrtf(np_sum64(w)), 1e-12f);
  #pragma unroll
  for (int d = 0; d < 64; d++) {
    float e = emb[(size_t)r * 64 + d];
    w[d] = t[d] * (e / mn);
  }
  float s = np_sum64(w);
  // Gumbel noise with f32 intermediate rounding, logs via double (approx. correctly-rounded f32 log)
  float u  = u01_from_key(kna, knb, (uint32_t)r);
  float l1 = (float)log((double)u);
  float l2 = (float)log((double)(-l1));
  s = s + (-l2);
  uint32_t b = __float_as_uint(s);
  m_arr[r] = b ^ (uint32_t)(((int32_t)b >> 31) | (int32_t)0x80000000);
  out_scores[r] = s;
}

// ---------------- exact top-1024: ONE single-workgroup kernel ----------------
// 4-pass radix selection with LDS histogram, LDS collect, LDS bitonic sort.
// Replaces 9 kernels whose global-memory histogram atomics cost 351 us/pass.
__global__ void __launch_bounds__(1024)
k_topk(const uint32_t* __restrict__ m_arr, float* __restrict__ out) {
  __shared__ uint32_t hist[256];
  __shared__ uint32_t selp, need, ccnt;
  __shared__ unsigned long long cbuf[4096];
  int tid = threadIdx.x;
  if (tid == 0) { selp = 0u; need = NCAND; ccnt = 0u; }
  __syncthreads();
  for (int shift = 24; shift >= 0; shift -= 8) {
    if (tid < 256) hist[tid] = 0u;
    __syncthreads();
    uint32_t pref = selp;
    for (int i = tid; i < NN; i += 1024) {
      uint32_t m = m_arr[i];
      bool ok = (shift == 24) || ((m >> (shift + 8)) == pref);
      if (ok) atomicAdd(&hist[(m >> shift) & 255u], 1u);
    }
    __syncthreads();
    if (tid == 0) {
      uint32_t nd = need;
      int b;
      for (b = 255; b > 0; b--) {
        uint32_t c = hist[b];
        if (c < nd) nd -= c; else break;
      }
      selp = (pref << 8) | (uint32_t)b;
      need = nd;
    }
    __syncthreads();
  }
  uint32_t thr = selp;
  for (int i = tid; i < NN; i += 1024) {
    uint32_t m = m_arr[i];
    if (m >= thr) {
      uint32_t pos = atomicAdd(&ccnt, 1u);
      if (pos < 4096u)
        cbuf[pos] = ((unsigned long long)m << 32) | (uint32_t)(~(uint32_t)i);
    }
  }
  __syncthreads();
  uint32_t n = ccnt; if (n > 4096u) n = 4096u;
  for (int i = tid; i < 4096; i += 1024) if (i >= (int)n) cbuf[i] = 0ULL;
  __syncthreads();
  for (int k = 2; k <= 4096; k <<= 1) {
    for (int j = k >> 1; j > 0; j >>= 1) {
      for (int i = tid; i < 4096; i += 1024) {
        int ixj = i ^ j;
        if (ixj > i) {
          bool up = ((i & k) == 0);
          unsigned long long a = cbuf[i], b = cbuf[ixj];
          if ((a > b) == up) { cbuf[i] = b; cbuf[ixj] = a; }
        }
      }
      __syncthreads();
    }
  }
  for (int j = tid; j < NCAND; j += 1024) {
    unsigned long long key = cbuf[4095 - j];
    uint32_t idx = ~(uint32_t)(key & 0xFFFFFFFFull);
    out[j] = (float)idx;
  }
}

// ---------------- launcher ----------------
extern "C" void kernel_launch(void* const* d_in, const int* in_sizes, int n_in,
                              void* d_out, int out_size, void* d_ws, size_t ws_size,
                              hipStream_t stream) {
  (void)in_sizes; (void)n_in; (void)out_size; (void)ws_size;
  const int*   rows = (const int*)d_in[0];
  const int*   cols = (const int*)d_in[1];
  const float* vals = (const float*)d_in[2];
  const float* emb  = (const float*)d_in[3];
  float* out = (float*)d_out;   // f32: scores[NN] then candidates[1024]

  // workspace carve (aligned 256B); total ~145 MB
  char* w = (char*)d_ws;
  auto alloc = [&](size_t bytes) -> void* {
    void* p = (void*)w; w += (bytes + 255) & ~(size_t)255; return p;
  };
  uint32_t* total   = (uint32_t*)alloc((size_t)NN * 4);   // adjacent: one memset
  uint32_t* cursor  = (uint32_t*)alloc((size_t)NN * 4);   // covers both
  uint32_t* rstart  = (uint32_t*)alloc((size_t)(NN + 1) * 4);
  uint32_t* bsum    = (uint32_t*)alloc((size_t)SCAN_BLOCKS * 4);
  uint32_t* scol    = (uint32_t*)alloc((size_t)NE * 4);
  uint32_t* seid    = (uint32_t*)alloc((size_t)NE * 4);
  float*    v0s     = (float*)alloc((size_t)NE * 4);
  float*    vAs     = (float*)alloc((size_t)NE * 4);
  float*    vBs     = (float*)alloc((size_t)NE * 4);
  float*    order0  = (float*)alloc((size_t)NN * 4);
  float*    order1  = (float*)alloc((size_t)NN * 4);
  float*    num0    = (float*)alloc((size_t)NN * 4);
  float*    num_sum = (float*)alloc((size_t)NN * 4);
  float*    fst     = (float*)alloc((size_t)NN * 64 * 4);
  float*    emb1    = (float*)alloc((size_t)NN * 64 * 4);
  float*    esum    = (float*)alloc((size_t)NN * 64 * 4);
  uint32_t* m_arr   = (uint32_t*)alloc((size_t)NN * 4);

  // host-side threefry key chain (data-independent):
  // key0=(0,42); key,kd = split(key) twice; key,kn = split(key)
  uint32_t K1a,K1b, kd0a,kd0b, K2a,K2b, kd1a,kd1b, kna,knb;
  tf2x32(0u, 42u, 0u, 0u, K1a, K1b);
  tf2x32(0u, 42u, 0u, 1u, kd0a, kd0b);
  tf2x32(K1a, K1b, 0u, 0u, K2a, K2b);
  tf2x32(K1a, K1b, 0u, 1u, kd1a, kd1b);
  tf2x32(K2a, K2b, 0u, 1u, kna, knb);

  // zero total + cursor (adjacent allocations, padded to 256B each)
  hipMemsetAsync(total, 0, ((size_t)NN * 4 + 255 & ~(size_t)255) * 2, stream);

  const int TPB = 256;
  k_histrows<<<(NE + TPB - 1) / TPB, TPB, 0, stream>>>(rows, total);
  k_scan1<<<SCAN_BLOCKS, 1024, 0, stream>>>(total, rstart, bsum);
  k_scan2<<<1, 1, 0, stream>>>(bsum);
  k_scan3<<<SCAN_BLOCKS, 1024, 0, stream>>>(rstart, bsum);
  k_scatter2<<<(NE + TPB - 1) / TPB, TPB, 0, stream>>>(rows, rstart, cursor, seid);
  k_rowsort<<<(NN + TPB - 1) / TPB, TPB, 0, stream>>>(rstart, seid);
  k_maskvals<<<(NE + TPB - 1) / TPB, TPB, 0, stream>>>(seid, cols, vals, scol, v0s, vAs, vBs,
                                                       kd0a, kd0b, kd1a, kd1b);
  k_rowsum<<<(NN + TPB - 1) / TPB, TPB, 0, stream>>>(rstart, v0s, vAs, order0, order1);
  k_fst<<<NN, 64, 0, stream>>>(rstart, scol, v0s, emb, fst, esum);
  k_numA<<<(NN + TPB - 1) / TPB, TPB, 0, stream>>>(rstart, scol, vAs, order0, num0, num_sum);
  k_emb1<<<NN, 64, 0, stream>>>(rstart, scol, vAs, fst, order0, emb1, esum);
  k_numB<<<(NN + TPB - 1) / TPB, TPB, 0, stream>>>(rstart, scol, vBs, num0, order1, num_sum);
  k_emb2<<<NN, 64, 0, stream>>>(rstart, scol, vBs, emb1, order1, esum);
  k_scores<<<(NN + TPB - 1) / TPB, TPB, 0, stream>>>(esum, num_sum, emb, m_arr, out, kna, knb);
  k_topk<<<1, 1024, 0, stream>>>(m_arr, out + NN);
}